// Round 4
// baseline (584.059 us; speedup 1.0000x reference)
//
#include <hip/hip_runtime.h>

// S4D real: y[l,c] = sum_s w[c,s] * h_s[l],  h_s[l] = x[l,c] + r[c,s]*h_s[l-1]
//
// R9: single fused kernel with a hand-rolled device-scope grid barrier.
// Evidence: R5->R7 (remove 1 dispatch, halve carry) = -1.1us; R8 (occupancy/
// TLP/sync tuning) = -3.5us regression => kernel internals are not the cost;
// dispatch boundaries + fixed harness fill are. R6's cooperative-launch fused
// attempt died in the harness (hipLaunchCooperativeKernel vs graph capture);
// this version uses a PLAIN <<<>>> launch + software barrier:
//   - __launch_bounds__(256,4): VGPR<=128 -> 4 blocks/CU; LDS 16KB<=40KB;
//     grid=1024 = 4*256CU -> ALL blocks co-resident -> barrier cannot starve.
//   - barrier counter in ws, zeroed by a 64B hipMemsetAsync before launch
//     (ws is poisoned every iteration; memset is graph-capturable - the
//     harness's own 256MiB poison fill is the same mechanism).
//   - bounded spin (~4M polls) so a logic bug fails the numeric check
//     instead of hanging the container.
// Phase math identical to the PASSING R7/R8 kernels:
//   A  : per-chunk local scan (params in-register), write chunk-end states
//   B1 : 8 groups x 16 chunks per (s,c): group aggregates -> aggbuf
//   B2 : cross-group prefix from aggbuf -> per-chunk carry-INs (in place)
//   C  : seeded re-scan + y = sum_s w*h (LDS cross-wave reduce)

namespace {

constexpr int L_ = 4096;
constexpr int CH_ = 512;
constexpr int S_ = 64;
constexpr float DT = 1.0f / 4096.0f;
constexpr int SC = S_ * CH_;   // 32768 (s,c) pairs
constexpr int SG = 16;         // states per thread (S_ / 4 waves)
constexpr int T_ = 32;         // chunk length
constexpr int NC_ = L_ / T_;   // 128 chunks
constexpr int GJ = 16;         // chunks per combine thread
constexpr int NJ = NC_ / GJ;   // 8 combine groups per (s,c)
constexpr int LB = 16;         // l-rows per LDS reduce round
constexpr int NB = NC_ * 8;    // 1024 blocks

__device__ __forceinline__ void grid_barrier(unsigned* __restrict__ ctr,
                                             unsigned target) {
  __syncthreads();
  if (threadIdx.x == 0) {
    __threadfence();  // release: publish this block's global writes
    __hip_atomic_fetch_add(ctr, 1u, __ATOMIC_RELEASE, __HIP_MEMORY_SCOPE_AGENT);
    // Bounded spin: worst case ~0.5s, then proceed (numeric check will fail
    // loudly instead of the container dying on a hang).
    for (int it = 0; it < (1 << 22); ++it) {
      if (__hip_atomic_load(ctr, __ATOMIC_ACQUIRE,
                            __HIP_MEMORY_SCOPE_AGENT) >= target)
        break;
      __builtin_amdgcn_s_sleep(2);
    }
    __threadfence();  // acquire: import other blocks' writes
  }
  __syncthreads();
}

// Compute r (and optionally w) for states [s0, s0+16) of channel c.
__device__ __forceinline__ void params16(const float* __restrict__ la,
                                         const float* __restrict__ Bg,
                                         const float* __restrict__ Cg,
                                         int c, int s0, float* r, float* w) {
  const float4* lap = reinterpret_cast<const float4*>(la + c * S_ + s0);
  if (w == nullptr) {
#pragma unroll
    for (int q = 0; q < 4; ++q) {
      const float4 v = lap[q];
      const float a[4] = {v.x, v.y, v.z, v.w};
#pragma unroll
      for (int t = 0; t < 4; ++t) {
        const float A = -expf(a[t]);
        r[q * 4 + t] = expf(A * DT);
      }
    }
  } else {
    const float4* bp = reinterpret_cast<const float4*>(Bg + c * S_ + s0);
    const float4* cp = reinterpret_cast<const float4*>(Cg + c * S_ + s0);
#pragma unroll
    for (int q = 0; q < 4; ++q) {
      const float4 v = lap[q], bb = bp[q], cc = cp[q];
      const float a[4] = {v.x, v.y, v.z, v.w};
      const float bv[4] = {bb.x, bb.y, bb.z, bb.w};
      const float cv[4] = {cc.x, cc.y, cc.z, cc.w};
#pragma unroll
      for (int t = 0; t < 4; ++t) {
        const float A = -expf(a[t]);
        const float rr = expf(A * DT);
        r[q * 4 + t] = rr;
        w[q * 4 + t] = cv[t] * ((rr - 1.0f) * bv[t] / A);
      }
    }
  }
}

// ---------------------------------------------------------------------------
__global__ __launch_bounds__(256, 4)
void s4d_fused(const float* __restrict__ x,
               const float* __restrict__ la,
               const float* __restrict__ Bg,
               const float* __restrict__ Cg,
               float* __restrict__ carry,    // [NC_][SC]
               float* __restrict__ aggbuf,   // [NJ][SC]
               unsigned* __restrict__ ctr,   // barrier counter (zeroed by memset)
               float* __restrict__ y) {
  __shared__ float lds[4][LB][64];  // 16 KB

  const int tid = threadIdx.x;
  const int bid = blockIdx.x;
  const int lane = tid & 63;
  const int g = tid >> 6;          // wave id: states [16g, 16g+16)
  const int k = bid >> 3;          // chunk
  const int cb = (bid & 7) << 6;   // channel-block base
  const int c = cb + lane;
  const int s0 = g * SG;

  // ---------------- Phase A: local scan, zero carry-in -> chunk ends --------
  {
    float r[SG], h[SG];
    params16(la, nullptr, nullptr, c, s0, r, nullptr);
#pragma unroll
    for (int i = 0; i < SG; ++i) h[i] = 0.0f;

    const float* xp = x + k * T_ * CH_ + c;
#pragma unroll 8
    for (int l = 0; l < T_; ++l) {
      const float xv = xp[l * CH_];
#pragma unroll
      for (int i = 0; i < SG; ++i) h[i] = fmaf(r[i], h[i], xv);
    }

    float* cw = carry + k * SC + s0 * CH_ + c;
#pragma unroll
    for (int i = 0; i < SG; ++i) cw[i * CH_] = h[i];
  }

  grid_barrier(ctr, 1u * NB);

  // ---------------- Phase B1: per-group aggregates --------------------------
  // Re-identity: thread (j, pid) owns chunks [GJ*j, GJ*j+GJ) of pid=(s,c).
  const int gt = bid * 256 + tid;   // 0 .. 262143
  const int j = gt >> 15;           // 0..7, uniform per block
  const int pid = gt & (SC - 1);
  float v[GJ];
  float rT;
  {
    const int sB = pid >> 9;
    const int cB = pid & (CH_ - 1);
    const float A = -expf(la[cB * S_ + sB]);
    rT = expf(A * (DT * (float)T_));  // r^T
#pragma unroll
    for (int m = 0; m < GJ; ++m) v[m] = carry[(j * GJ + m) * SC + pid];
    float agg = 0.0f;
#pragma unroll
    for (int m = 0; m < GJ; ++m) agg = fmaf(rT, agg, v[m]);
    aggbuf[j * SC + pid] = agg;
  }

  grid_barrier(ctr, 2u * NB);

  // ---------------- Phase B2: cross-group prefix -> carry-ins in place ------
  {
    float rTG = rT * rT;  // rT^2
    rTG *= rTG;           // ^4
    rTG *= rTG;           // ^8
    rTG *= rTG;           // ^16 = rT^GJ
    float G = 0.0f;       // carry-in of group j
    for (int j2 = 0; j2 < j; ++j2) G = fmaf(rTG, G, aggbuf[j2 * SC + pid]);
    float st = G;
#pragma unroll
    for (int m = 0; m < GJ; ++m) {
      carry[(j * GJ + m) * SC + pid] = st;  // carry-IN of chunk GJ*j+m
      st = fmaf(rT, st, v[m]);
    }
  }

  grid_barrier(ctr, 3u * NB);

  // ---------------- Phase C: seeded re-scan + output ------------------------
  {
    float r[SG], w[SG], h[SG];
    params16(la, Bg, Cg, c, s0, r, w);

    const float* crd = carry + k * SC + s0 * CH_ + c;
#pragma unroll
    for (int i = 0; i < SG; ++i) h[i] = crd[i * CH_];

    const float* xp = x + k * T_ * CH_ + c;
    float* yp = y + k * T_ * CH_;

    for (int l = 0; l < T_; l += LB) {
      float part[LB];
#pragma unroll
      for (int jj = 0; jj < LB; ++jj) {
        const float xv = xp[(l + jj) * CH_];
        float a0 = 0, a1 = 0, a2 = 0, a3 = 0;
#pragma unroll
        for (int i = 0; i < SG; i += 4) {
          h[i]     = fmaf(r[i],     h[i],     xv);
          h[i + 1] = fmaf(r[i + 1], h[i + 1], xv);
          h[i + 2] = fmaf(r[i + 2], h[i + 2], xv);
          h[i + 3] = fmaf(r[i + 3], h[i + 3], xv);
          a0 = fmaf(w[i],     h[i],     a0);
          a1 = fmaf(w[i + 1], h[i + 1], a1);
          a2 = fmaf(w[i + 2], h[i + 2], a2);
          a3 = fmaf(w[i + 3], h[i + 3], a3);
        }
        part[jj] = (a0 + a1) + (a2 + a3);
      }

#pragma unroll
      for (int jj = 0; jj < LB; ++jj) lds[g][jj][lane] = part[jj];
      __syncthreads();
#pragma unroll
      for (int p = 0; p < LB * 64 / 256; ++p) {
        const int idx = tid + p * 256;
        const int jj = idx >> 6;
        const int ln = idx & 63;
        const float vv = (lds[0][jj][ln] + lds[1][jj][ln]) +
                         (lds[2][jj][ln] + lds[3][jj][ln]);
        yp[(l + jj) * CH_ + cb + ln] = vv;
      }
      __syncthreads();
    }
  }
}

// ======================= Fallback: proven 3-kernel path =====================
template <int T>
__global__ __launch_bounds__(256) void k_local(const float* __restrict__ x,
                                               const float* __restrict__ la,
                                               float* __restrict__ carry) {
  const int lane = threadIdx.x & 63;
  const int g = threadIdx.x >> 6;
  const int k = blockIdx.x >> 3;
  const int c = ((blockIdx.x & 7) << 6) + lane;
  const int s0 = g * SG;

  float r[SG], h[SG];
  params16(la, nullptr, nullptr, c, s0, r, nullptr);
#pragma unroll
  for (int i = 0; i < SG; ++i) h[i] = 0.0f;
  const float* xp = x + (size_t)k * T * CH_ + c;
#pragma unroll 8
  for (int l = 0; l < T; ++l) {
    const float xv = xp[l * CH_];
#pragma unroll
    for (int i = 0; i < SG; ++i) h[i] = fmaf(r[i], h[i], xv);
  }
  float* cw = carry + (size_t)k * SC + s0 * CH_ + c;
#pragma unroll
  for (int i = 0; i < SG; ++i) cw[i * CH_] = h[i];
}

template <int NCF, int GJF>
__global__ __launch_bounds__(256) void k_comb(const float* __restrict__ la,
                                              float* __restrict__ carry) {
  __shared__ float aggs[NCF / GJF][64];
  const int p = threadIdx.x & 63;
  const int j = threadIdx.x >> 6;
  const int pid = (blockIdx.x << 6) + p;
  const int s = pid >> 9;
  const int c = pid & (CH_ - 1);

  const float A = -expf(la[c * S_ + s]);
  const float rT = expf(A * (DT * (float)(L_ / NCF)));
  float rTG = rT;
#pragma unroll
  for (int t = 1; t < GJF; t <<= 1) rTG *= rTG;

  float v[GJF];
#pragma unroll
  for (int m = 0; m < GJF; ++m) v[m] = carry[(size_t)(j * GJF + m) * SC + pid];
  float agg = 0.0f;
#pragma unroll
  for (int m = 0; m < GJF; ++m) agg = fmaf(rT, agg, v[m]);
  aggs[j][p] = agg;
  __syncthreads();
  float G = 0.0f;
  for (int j2 = 0; j2 < j; ++j2) G = fmaf(rTG, G, aggs[j2][p]);
  float st = G;
#pragma unroll
  for (int m = 0; m < GJF; ++m) {
    carry[(size_t)(j * GJF + m) * SC + pid] = st;
    st = fmaf(rT, st, v[m]);
  }
}

template <int T, bool USE_CARRY>
__global__ __launch_bounds__(256) void k_scan(const float* __restrict__ x,
                                              const float* __restrict__ la,
                                              const float* __restrict__ Bg,
                                              const float* __restrict__ Cg,
                                              const float* __restrict__ carry,
                                              float* __restrict__ y) {
  __shared__ float lds[4][8][64];
  const int lane = threadIdx.x & 63;
  const int g = threadIdx.x >> 6;
  const int k = blockIdx.x >> 3;
  const int cb = (blockIdx.x & 7) << 6;
  const int c = cb + lane;
  const int s0 = g * SG;

  float r[SG], w[SG], h[SG];
  params16(la, Bg, Cg, c, s0, r, w);
  if (USE_CARRY) {
    const float* crd = carry + (size_t)k * SC + s0 * CH_ + c;
#pragma unroll
    for (int i = 0; i < SG; ++i) h[i] = crd[i * CH_];
  } else {
#pragma unroll
    for (int i = 0; i < SG; ++i) h[i] = 0.0f;
  }
  const float* xp = x + (size_t)k * T * CH_ + c;
  float* yp = y + (size_t)k * T * CH_;

  for (int l = 0; l < T; l += 8) {
    float part[8];
#pragma unroll
    for (int jj = 0; jj < 8; ++jj) {
      const float xv = xp[(l + jj) * CH_];
      float a0 = 0, a1 = 0, a2 = 0, a3 = 0;
#pragma unroll
      for (int i = 0; i < SG; i += 4) {
        h[i]     = fmaf(r[i],     h[i],     xv);
        h[i + 1] = fmaf(r[i + 1], h[i + 1], xv);
        h[i + 2] = fmaf(r[i + 2], h[i + 2], xv);
        h[i + 3] = fmaf(r[i + 3], h[i + 3], xv);
        a0 = fmaf(w[i],     h[i],     a0);
        a1 = fmaf(w[i + 1], h[i + 1], a1);
        a2 = fmaf(w[i + 2], h[i + 2], a2);
        a3 = fmaf(w[i + 3], h[i + 3], a3);
      }
      part[jj] = (a0 + a1) + (a2 + a3);
    }
#pragma unroll
    for (int jj = 0; jj < 8; ++jj) lds[g][jj][lane] = part[jj];
    __syncthreads();
#pragma unroll
    for (int p = 0; p < 2; ++p) {
      const int idx = (int)threadIdx.x + p * 256;
      const int jj = idx >> 6;
      const int ln = idx & 63;
      const float vv = (lds[0][jj][ln] + lds[1][jj][ln]) +
                       (lds[2][jj][ln] + lds[3][jj][ln]);
      yp[(size_t)(l + jj) * CH_ + cb + ln] = vv;
    }
    __syncthreads();
  }
}

}  // namespace

extern "C" void kernel_launch(void* const* d_in, const int* in_sizes, int n_in,
                              void* d_out, int out_size, void* d_ws, size_t ws_size,
                              hipStream_t stream) {
  const float* x = (const float*)d_in[0];
  const float* la = (const float*)d_in[1];
  const float* B = (const float*)d_in[2];
  const float* C = (const float*)d_in[3];
  float* y = (float*)d_out;
  float* ws = (float*)d_ws;

  const size_t carry_f = (size_t)NC_ * SC;         // 16 MB
  const size_t agg_f = (size_t)NJ * SC;            // 1 MB
  const size_t need = (carry_f + agg_f) * sizeof(float) + 64;
  if (ws_size >= need) {
    float* carry = ws;
    float* aggbuf = ws + carry_f;
    unsigned* ctr = (unsigned*)(ws + carry_f + agg_f);
    hipMemsetAsync((void*)ctr, 0, 64, stream);
    s4d_fused<<<NB, 256, 0, stream>>>(x, la, B, C, carry, aggbuf, ctr, y);
    return;
  }

  // Fallback (never expected with 256MiB ws): proven 3-dispatch path, T=64.
  constexpr int TF = 64;
  constexpr int NCF = L_ / TF;
  if (ws_size >= (size_t)NCF * SC * sizeof(float)) {
    float* carry = ws;
    k_local<TF><<<NCF * 8, 256, 0, stream>>>(x, la, carry);
    k_comb<NCF, 16><<<SC / 64, 256, 0, stream>>>(la, carry);
    k_scan<TF, true><<<NCF * 8, 256, 0, stream>>>(x, la, B, C, carry, y);
  } else {
    k_scan<L_, false><<<8, 256, 0, stream>>>(x, la, B, C, nullptr, y);
  }
}

// Round 5
// 107.554 us; speedup vs baseline: 5.4304x; 5.4304x over previous
//
#include <hip/hip_runtime.h>

// S4D real: y[l,c] = sum_s w[c,s] * h_s[l],  h_s[l] = x[l,c] + r[c,s]*h_s[l-1]
//
// R10: TWO plain dispatches, no global barrier, no atomics.
// R9 autopsy: fused kernel passed but spent ~510us in barrier spin (1024
// pollers on ONE cacheline with agent-scope atomic loads). Window model is
// now confirmed: dur ~= 43us harness fill + sum(dispatches) + ~3us/boundary.
// R7's three kernels cost ~41us; k_comb alone is a 16MB read + 16MB write +
// a boundary. This version eliminates it algebraically:
//   K1 k_strip: 16 strips x 8 chunks. Block scans 8 chunks (256 steps) from
//     zero, writing the within-strip inclusive state at EVERY chunk boundary
//     into P[k][s][c] (k = 8g+m; same 16MB layout as the old carry).
//   K2 k_scan2: block for chunk k=8g+m rebuilds its true carry-in in regs:
//     G_g = Horner_{g'<g}( rT8, P[g'][7] )   (strip aggregates, L2-hot)
//     h0  = (m? P[g][m-1] : 0) + rT^m * G_g
//     then the PASSING R7 seeded chunk scan + LDS cross-wave y reduce.
// Linear-recurrence algebra: state after strip g (true) = local + r^256 * in,
// so G_{g+1} = P[g][7] + rT8*G_g; carry-in(8g+m) = P[g][m-1] + rT^m * G_g.

namespace {

constexpr int L_ = 4096;
constexpr int CH_ = 512;
constexpr int S_ = 64;
constexpr float DT = 1.0f / 4096.0f;
constexpr int SC = S_ * CH_;   // 32768 (s,c) pairs
constexpr int SG = 16;         // states per thread (S_ / 4 waves)
constexpr int T_ = 32;         // chunk length
constexpr int NC_ = L_ / T_;   // 128 chunks
constexpr int CPS = 8;         // chunks per strip
constexpr int NS = NC_ / CPS;  // 16 strips

// Compute r (and optionally w) for states [s0, s0+16) of channel c.
__device__ __forceinline__ void params16(const float* __restrict__ la,
                                         const float* __restrict__ Bg,
                                         const float* __restrict__ Cg,
                                         int c, int s0, float* r, float* w) {
  const float4* lap = reinterpret_cast<const float4*>(la + c * S_ + s0);
  if (w == nullptr) {
#pragma unroll
    for (int q = 0; q < 4; ++q) {
      const float4 v = lap[q];
      const float a[4] = {v.x, v.y, v.z, v.w};
#pragma unroll
      for (int t = 0; t < 4; ++t) {
        const float A = -expf(a[t]);
        r[q * 4 + t] = expf(A * DT);
      }
    }
  } else {
    const float4* bp = reinterpret_cast<const float4*>(Bg + c * S_ + s0);
    const float4* cp = reinterpret_cast<const float4*>(Cg + c * S_ + s0);
#pragma unroll
    for (int q = 0; q < 4; ++q) {
      const float4 v = lap[q], bb = bp[q], cc = cp[q];
      const float a[4] = {v.x, v.y, v.z, v.w};
      const float bv[4] = {bb.x, bb.y, bb.z, bb.w};
      const float cv[4] = {cc.x, cc.y, cc.z, cc.w};
#pragma unroll
      for (int t = 0; t < 4; ++t) {
        const float A = -expf(a[t]);
        const float rr = expf(A * DT);
        r[q * 4 + t] = rr;
        w[q * 4 + t] = cv[t] * ((rr - 1.0f) * bv[t] / A);
      }
    }
  }
}

// ---------------- K1: strip scan, write state at every chunk boundary -------
// grid = NS*8 = 128 blocks, 256 thr (4 waves x 16 states, lane = channel).
__global__ __launch_bounds__(256, 4)
void k_strip(const float* __restrict__ x, const float* __restrict__ la,
             float* __restrict__ P) {
  const int lane = threadIdx.x & 63;
  const int g = threadIdx.x >> 6;       // wave: states [16g, 16g+16)
  const int strip = blockIdx.x >> 3;    // 0..NS-1
  const int cb = (blockIdx.x & 7) << 6;
  const int c = cb + lane;
  const int s0 = g * SG;

  float r[SG], h[SG];
  params16(la, nullptr, nullptr, c, s0, r, nullptr);
#pragma unroll
  for (int i = 0; i < SG; ++i) h[i] = 0.0f;

  const float* xp = x + (size_t)strip * CPS * T_ * CH_ + c;
  float* pp = P + (size_t)strip * CPS * SC + s0 * CH_ + c;

  for (int m = 0; m < CPS; ++m) {
#pragma unroll 8
    for (int l = 0; l < T_; ++l) {
      const float xv = xp[(m * T_ + l) * CH_];
#pragma unroll
      for (int i = 0; i < SG; ++i) h[i] = fmaf(r[i], h[i], xv);
    }
    float* pm = pp + (size_t)m * SC;
#pragma unroll
    for (int i = 0; i < SG; ++i) pm[i * CH_] = h[i];  // within-strip incl. end
  }
}

// ---------------- K2: carry-in from P (in regs) + seeded scan + output ------
// grid = NC*8 = 1024 blocks. Block handles chunk k = 8g+m, channel block cb.
__global__ __launch_bounds__(256, 4)
void k_scan2(const float* __restrict__ x, const float* __restrict__ la,
             const float* __restrict__ Bg, const float* __restrict__ Cg,
             const float* __restrict__ P, float* __restrict__ y) {
  __shared__ float lds[4][8][64];  // [s-group][l-row][lane]

  const int lane = threadIdx.x & 63;
  const int g = threadIdx.x >> 6;
  const int k = blockIdx.x >> 3;
  const int cb = (blockIdx.x & 7) << 6;
  const int c = cb + lane;
  const int s0 = g * SG;
  const int gs = k >> 3;   // strip   (CPS = 8)
  const int m = k & 7;     // chunk within strip

  float r[SG], w[SG], h[SG];
  params16(la, Bg, Cg, c, s0, r, w);

  // rT = r^T (5 squarings), rT8 = rT^CPS (3 more).
  float rT[SG], rT8[SG];
#pragma unroll
  for (int i = 0; i < SG; ++i) {
    float t = r[i];
    t *= t; t *= t; t *= t; t *= t; t *= t;  // r^32
    rT[i] = t;
    t *= t; t *= t; t *= t;                  // r^256
    rT8[i] = t;
  }

  // G = true state at strip start: Horner over strip aggregates P[g'][CPS-1].
  float G[SG];
#pragma unroll
  for (int i = 0; i < SG; ++i) G[i] = 0.0f;
  for (int gp = 0; gp < gs; ++gp) {
    const float* ap = P + ((size_t)gp * CPS + (CPS - 1)) * SC + s0 * CH_ + c;
#pragma unroll
    for (int i = 0; i < SG; ++i) G[i] = fmaf(rT8[i], G[i], ap[i * CH_]);
  }
  // Advance G across m chunks within the strip: G *= rT^m.
  for (int t2 = 0; t2 < m; ++t2) {
#pragma unroll
    for (int i = 0; i < SG; ++i) G[i] *= rT[i];
  }
  // h0 = (m ? P[g][m-1] : 0) + G
  if (m == 0) {
#pragma unroll
    for (int i = 0; i < SG; ++i) h[i] = G[i];
  } else {
    const float* prev = P + (size_t)(k - 1) * SC + s0 * CH_ + c;
#pragma unroll
    for (int i = 0; i < SG; ++i) h[i] = G[i] + prev[i * CH_];
  }

  const float* xp = x + (size_t)k * T_ * CH_ + c;
  float* yp = y + (size_t)k * T_ * CH_;

  for (int l = 0; l < T_; l += 8) {
    float part[8];
#pragma unroll
    for (int jj = 0; jj < 8; ++jj) {
      const float xv = xp[(l + jj) * CH_];
      float a0 = 0, a1 = 0, a2 = 0, a3 = 0;
#pragma unroll
      for (int i = 0; i < SG; i += 4) {
        h[i]     = fmaf(r[i],     h[i],     xv);
        h[i + 1] = fmaf(r[i + 1], h[i + 1], xv);
        h[i + 2] = fmaf(r[i + 2], h[i + 2], xv);
        h[i + 3] = fmaf(r[i + 3], h[i + 3], xv);
        a0 = fmaf(w[i],     h[i],     a0);
        a1 = fmaf(w[i + 1], h[i + 1], a1);
        a2 = fmaf(w[i + 2], h[i + 2], a2);
        a3 = fmaf(w[i + 3], h[i + 3], a3);
      }
      part[jj] = (a0 + a1) + (a2 + a3);
    }

#pragma unroll
    for (int jj = 0; jj < 8; ++jj) lds[g][jj][lane] = part[jj];
    __syncthreads();
#pragma unroll
    for (int p = 0; p < 2; ++p) {
      const int idx = (int)threadIdx.x + p * 256;
      const int jj = idx >> 6;
      const int ln = idx & 63;
      const float vv = (lds[0][jj][ln] + lds[1][jj][ln]) +
                       (lds[2][jj][ln] + lds[3][jj][ln]);
      yp[(size_t)(l + jj) * CH_ + cb + ln] = vv;
    }
    __syncthreads();
  }
}

// ---------------- Degenerate fallback: full-length serial scan --------------
__global__ __launch_bounds__(256) void k_scan_full(const float* __restrict__ x,
                                                   const float* __restrict__ la,
                                                   const float* __restrict__ Bg,
                                                   const float* __restrict__ Cg,
                                                   float* __restrict__ y) {
  __shared__ float lds[4][8][64];
  const int lane = threadIdx.x & 63;
  const int g = threadIdx.x >> 6;
  const int cb = (blockIdx.x & 7) << 6;
  const int c = cb + lane;
  const int s0 = g * SG;

  float r[SG], w[SG], h[SG];
  params16(la, Bg, Cg, c, s0, r, w);
#pragma unroll
  for (int i = 0; i < SG; ++i) h[i] = 0.0f;

  const float* xp = x + c;
  float* yp = y;

  for (int l = 0; l < L_; l += 8) {
    float part[8];
#pragma unroll
    for (int jj = 0; jj < 8; ++jj) {
      const float xv = xp[(size_t)(l + jj) * CH_];
      float a0 = 0, a1 = 0, a2 = 0, a3 = 0;
#pragma unroll
      for (int i = 0; i < SG; i += 4) {
        h[i]     = fmaf(r[i],     h[i],     xv);
        h[i + 1] = fmaf(r[i + 1], h[i + 1], xv);
        h[i + 2] = fmaf(r[i + 2], h[i + 2], xv);
        h[i + 3] = fmaf(r[i + 3], h[i + 3], xv);
        a0 = fmaf(w[i],     h[i],     a0);
        a1 = fmaf(w[i + 1], h[i + 1], a1);
        a2 = fmaf(w[i + 2], h[i + 2], a2);
        a3 = fmaf(w[i + 3], h[i + 3], a3);
      }
      part[jj] = (a0 + a1) + (a2 + a3);
    }
#pragma unroll
    for (int jj = 0; jj < 8; ++jj) lds[g][jj][lane] = part[jj];
    __syncthreads();
#pragma unroll
    for (int p = 0; p < 2; ++p) {
      const int idx = (int)threadIdx.x + p * 256;
      const int jj = idx >> 6;
      const int ln = idx & 63;
      const float vv = (lds[0][jj][ln] + lds[1][jj][ln]) +
                       (lds[2][jj][ln] + lds[3][jj][ln]);
      yp[(size_t)(l + jj) * CH_ + cb + ln] = vv;
    }
    __syncthreads();
  }
}

}  // namespace

extern "C" void kernel_launch(void* const* d_in, const int* in_sizes, int n_in,
                              void* d_out, int out_size, void* d_ws, size_t ws_size,
                              hipStream_t stream) {
  const float* x = (const float*)d_in[0];
  const float* la = (const float*)d_in[1];
  const float* B = (const float*)d_in[2];
  const float* C = (const float*)d_in[3];
  float* y = (float*)d_out;
  float* P = (float*)d_ws;

  const size_t need = (size_t)NC_ * SC * sizeof(float);  // 16 MB
  if (ws_size >= need) {
    k_strip<<<NS * 8, 256, 0, stream>>>(x, la, P);
    k_scan2<<<NC_ * 8, 256, 0, stream>>>(x, la, B, C, P, y);
  } else {
    k_scan_full<<<8, 256, 0, stream>>>(x, la, B, C, y);
  }
}